// Round 9
// baseline (166.555 us; speedup 1.0000x reference)
//
#include <hip/hip_runtime.h>
#include <math.h>

#define NB 4
#define NT 2048
#define ND 512
#define NH 8
#define NC 64
#define NM (NB*NT)
#define LN_EPS 1e-5f
#define SCL 0.18033688f   // (1/sqrt(64)) * log2(e)

typedef __attribute__((ext_vector_type(8))) short bf16x8;
typedef __attribute__((ext_vector_type(4))) float f32x4;
typedef __attribute__((ext_vector_type(16))) float f32x16;
typedef __attribute__((ext_vector_type(4))) unsigned int u32x4;

__device__ inline unsigned short f2b(float f) {
    unsigned int u = __builtin_bit_cast(unsigned int, f);
    u += 0x7FFFu + ((u >> 16) & 1u);
    return (unsigned short)(u >> 16);
}
__device__ inline unsigned cvtpk(float lo, float hi) {
    unsigned r;
    asm("v_cvt_pk_bf16_f32 %0, %1, %2" : "=v"(r) : "v"(lo), "v"(hi));
    return r;
}
__device__ inline void gload_lds16(const void* g, void* l) {
    __builtin_amdgcn_global_load_lds(
        (__attribute__((address_space(1))) void*)g,
        (__attribute__((address_space(3))) void*)l, 16, 0, 0);
}

// ---------------------------------------------------------------------------
// LayerNorm -> bf16 xn.
// ---------------------------------------------------------------------------
__global__ __launch_bounds__(256) void ln_kernel(const float* __restrict__ x,
        const float* __restrict__ gamma, const float* __restrict__ beta,
        unsigned short* __restrict__ xb) {
    const int row = blockIdx.x;
    const float* xr = x + (size_t)row * ND;
    const int t = threadIdx.x;

    float2 v = *(const float2*)(xr + 2*t);
    float s  = v.x + v.y;
    float ss = v.x*v.x + v.y*v.y;
    #pragma unroll
    for (int off = 1; off < 64; off <<= 1) {
        s  += __shfl_xor(s, off);
        ss += __shfl_xor(ss, off);
    }
    __shared__ float sb[4], ssb[4];
    if ((t & 63) == 0) { sb[t >> 6] = s; ssb[t >> 6] = ss; }
    __syncthreads();
    s  = sb[0] + sb[1] + sb[2] + sb[3];
    ss = ssb[0] + ssb[1] + ssb[2] + ssb[3];

    const float mu   = s * (1.0f / ND);
    const float var  = ss * (1.0f / ND) - mu * mu;
    const float rstd = rsqrtf(var + LN_EPS);

    float2 g  = *(const float2*)(gamma + 2*t);
    float2 be = *(const float2*)(beta + 2*t);
    ushort2 o;
    o.x = f2b((v.x - mu) * rstd * g.x + be.x);
    o.y = f2b((v.y - mu) * rstd * g.y + be.y);
    *(ushort2*)(xb + (size_t)row * ND + 2*t) = o;
}

// ---------------------------------------------------------------------------
// W fp32 -> bf16
// ---------------------------------------------------------------------------
__global__ __launch_bounds__(256) void wconv_kernel(const float* __restrict__ Wq,
        const float* __restrict__ Wk, const float* __restrict__ Wv,
        unsigned short* __restrict__ wb) {
    int idx = blockIdx.x * 256 + threadIdx.x;
    const float* src = (idx < 65536) ? Wq : (idx < 131072) ? Wk : Wv;
    int loc = idx & 65535;
    float4 f = *(const float4*)(src + (size_t)loc * 4);
    ushort4 o;
    o.x = f2b(f.x); o.y = f2b(f.y); o.z = f2b(f.z); o.w = f2b(f.w);
    *(ushort4*)(wb + (size_t)idx * 4) = o;
}

// ---------------------------------------------------------------------------
// QKV projection: 128x128 tile, BK=64, bf16 MFMA.
// z==2 (V) writes transposed vt[b][h][c][t].
// ---------------------------------------------------------------------------
__global__ __launch_bounds__(256) void qkv_gemm(const unsigned short* __restrict__ xb,
        const unsigned short* __restrict__ wb,
        unsigned short* __restrict__ qb, unsigned short* __restrict__ kb,
        unsigned short* __restrict__ vtb) {
    const int z  = blockIdx.z;
    const int bm = blockIdx.y * 128;
    const int bn = blockIdx.x * 128;
    const int t  = threadIdx.x;
    const int w = t >> 6, l = t & 63, lr = l & 15, lg = l >> 4;
    const int wm = w >> 1, wn = w & 1;

    __shared__ __attribute__((aligned(16))) unsigned short As[128 * 64];
    __shared__ __attribute__((aligned(16))) unsigned short Bs[128 * 64];
    const unsigned short* Wp = wb + (size_t)z * ND * ND;

    f32x4 acc[4][4];
    #pragma unroll
    for (int i = 0; i < 4; ++i)
        #pragma unroll
        for (int j = 0; j < 4; ++j) acc[i][j] = (f32x4){0.f, 0.f, 0.f, 0.f};

    for (int k0 = 0; k0 < ND; k0 += 64) {
        __syncthreads();
        #pragma unroll
        for (int i = 0; i < 4; ++i) {
            int ch = i * 256 + t;
            int r = ch >> 3, c16 = ch & 7;
            gload_lds16(xb + (size_t)(bm + r) * ND + k0 + c16 * 8, (char*)As + ch * 16);
            gload_lds16(Wp + (size_t)(bn + r) * ND + k0 + c16 * 8, (char*)Bs + ch * 16);
        }
        __syncthreads();
        #pragma unroll
        for (int ks = 0; ks < 2; ++ks) {
            bf16x8 af[4], bfr[4];
            #pragma unroll
            for (int mf = 0; mf < 4; ++mf)
                af[mf] = *(const bf16x8*)((const char*)As + (wm*64 + mf*16 + lr)*128 + ks*64 + lg*16);
            #pragma unroll
            for (int nf = 0; nf < 4; ++nf)
                bfr[nf] = *(const bf16x8*)((const char*)Bs + (wn*64 + nf*16 + lr)*128 + ks*64 + lg*16);
            #pragma unroll
            for (int mf = 0; mf < 4; ++mf)
                #pragma unroll
                for (int nf = 0; nf < 4; ++nf)
                    acc[mf][nf] = __builtin_amdgcn_mfma_f32_16x16x32_bf16(
                        af[mf], bfr[nf], acc[mf][nf], 0, 0, 0);
        }
    }

    if (z < 2) {
        unsigned short* outp = (z == 0) ? qb : kb;
        #pragma unroll
        for (int mf = 0; mf < 4; ++mf)
            #pragma unroll
            for (int r = 0; r < 4; ++r) {
                int grow = bm + wm*64 + mf*16 + lg*4 + r;
                #pragma unroll
                for (int nf = 0; nf < 4; ++nf) {
                    int gcol = bn + wn*64 + nf*16 + lr;
                    outp[(size_t)grow * ND + gcol] = f2b(acc[mf][nf][r]);
                }
            }
    } else {
        #pragma unroll
        for (int mf = 0; mf < 4; ++mf)
            #pragma unroll
            for (int r = 0; r < 4; ++r) {
                int grow = bm + wm*64 + mf*16 + lg*4 + r;
                int bb = grow >> 11, tt = grow & 2047;
                #pragma unroll
                for (int nf = 0; nf < 4; ++nf) {
                    int gcol = bn + wn*64 + nf*16 + lr;
                    int h = gcol >> 6, c = gcol & 63;
                    vtb[((size_t)(bb * NH + h) * NC + c) * NT + tt] = f2b(acc[mf][nf][r]);
                }
            }
    }
}

// ---------------------------------------------------------------------------
// Flash attention, swapped 32x32x16, NO LDS / NO barriers:
// per-lane K/V fragments loaded global->register (KV is L2-resident),
// software-pipelined one tile ahead; compiler emits counted vmcnt waits.
// No KV-split -> no combine kernel; epilogue fuses out = x + emb + O/l.
// Numerics verbatim from passing round 6.
// ---------------------------------------------------------------------------
__global__ __launch_bounds__(256, 2) void attn_kernel(
        const unsigned short* __restrict__ qb, const unsigned short* __restrict__ kb,
        const unsigned short* __restrict__ vtb,
        const float* __restrict__ x, const float* __restrict__ emb,
        float* __restrict__ out) {
    // bijective XCD swizzle: consecutive swizzled ids share an XCD so the
    // 16 q-blocks of one (b,h) stay L2-local (KV footprint 4MB = L2/XCD).
    int lin = blockIdx.x + 16 * (blockIdx.y + 8 * blockIdx.z);   // 512 blocks
    int wg  = (lin & 7) * 64 + (lin >> 3);
    const int qt = wg & 15, h = (wg >> 4) & 7, b = wg >> 7;

    const int t = threadIdx.x;
    const int w = t >> 6, l = t & 63;
    const int q32 = l & 31, hi = l >> 5;

    const size_t kbase = (size_t)(b * NT) * ND + h * NC;
    const size_t vbase = (size_t)(b * NH + h) * NC * NT;

    const int qrow = qt * 128 + w * 32 + q32;
    bf16x8 aq[4];
    #pragma unroll
    for (int cs = 0; cs < 4; ++cs)
        aq[cs] = *(const bf16x8*)(qb + (size_t)(b*NT + qrow) * ND + h*NC + cs*16 + hi*8);

    f32x16 oa[2];
    #pragma unroll
    for (int ct = 0; ct < 2; ++ct)
        #pragma unroll
        for (int r = 0; r < 16; ++r) oa[ct][r] = 0.f;
    float m = -1e30f, li = 0.f;

    // per-lane fragment loads (verified identical to the LDS-path values)
#define LOADK(dst, ktv)                                                         \
    _Pragma("unroll")                                                           \
    for (int ks_ = 0; ks_ < 2; ++ks_)                                           \
        _Pragma("unroll")                                                       \
        for (int cs_ = 0; cs_ < 4; ++cs_)                                       \
            dst[ks_][cs_] = *(const bf16x8*)(kb + kbase +                       \
                (size_t)((ktv) + ks_*32 + q32) * ND + cs_*16 + hi*8);
#define LOADV(dst, ktv)                                                         \
    _Pragma("unroll")                                                           \
    for (int j_ = 0; j_ < 4; ++j_)                                              \
        _Pragma("unroll")                                                       \
        for (int ct_ = 0; ct_ < 2; ++ct_)                                       \
            dst[j_][ct_] = *(const bf16x8*)(vtb + vbase +                       \
                (size_t)(ct_*32 + q32) * NT + (ktv) + j_*16 + hi*8);

    bf16x8 kc[2][4], vc[4][2];
    LOADK(kc, 0);
    LOADV(vc, 0);

    for (int it = 0; it < NT/64; ++it) {
        const int ktn = (it < NT/64 - 1) ? (it + 1) * 64 : it * 64;

        // S^T = K Q^T
        f32x16 sa[2];
        __builtin_amdgcn_s_setprio(1);
        #pragma unroll
        for (int ks = 0; ks < 2; ++ks) {
            #pragma unroll
            for (int r = 0; r < 16; ++r) sa[ks][r] = 0.f;
            #pragma unroll
            for (int cs = 0; cs < 4; ++cs)
                sa[ks] = __builtin_amdgcn_mfma_f32_32x32x16_bf16(kc[ks][cs], aq[cs], sa[ks], 0, 0, 0);
        }
        __builtin_amdgcn_s_setprio(0);

        // prefetch next K tile (in flight under softmax + PV)
        bf16x8 kn[2][4];
        LOADK(kn, ktn);

        // tile max: 3-input groups, cross-half via shfl_xor (proven)
        float a0 = fmaxf(fmaxf(sa[0][0],  sa[0][1]),  sa[0][2]);
        float a1 = fmaxf(fmaxf(sa[0][3],  sa[0][4]),  sa[0][5]);
        float a2 = fmaxf(fmaxf(sa[0][6],  sa[0][7]),  sa[0][8]);
        float a3 = fmaxf(fmaxf(sa[0][9],  sa[0][10]), sa[0][11]);
        float a4 = fmaxf(fmaxf(sa[0][12], sa[0][13]), sa[0][14]);
        float a5 = fmaxf(fmaxf(sa[0][15], sa[1][0]),  sa[1][1]);
        float a6 = fmaxf(fmaxf(sa[1][2],  sa[1][3]),  sa[1][4]);
        float a7 = fmaxf(fmaxf(sa[1][5],  sa[1][6]),  sa[1][7]);
        float a8 = fmaxf(fmaxf(sa[1][8],  sa[1][9]),  sa[1][10]);
        float a9 = fmaxf(fmaxf(sa[1][11], sa[1][12]), sa[1][13]);
        float b0 = fmaxf(fmaxf(a0, a1), a2);
        float b1 = fmaxf(fmaxf(a3, a4), a5);
        float b2 = fmaxf(fmaxf(a6, a7), a8);
        float b3 = fmaxf(fmaxf(a9, sa[1][14]), sa[1][15]);
        float tm = fmaxf(fmaxf(b0, b1), fmaxf(b2, b3));
        tm = fmaxf(tm, __shfl_xor(tm, 32));

        // defer-max (THR=8 in exp2 domain)
        if (__any((tm - m) * SCL > 8.0f)) {
            float nm = fmaxf(m, tm);
            float f = __builtin_amdgcn_exp2f((m - nm) * SCL);
            m = nm; li *= f;
            #pragma unroll
            for (int ct = 0; ct < 2; ++ct)
                #pragma unroll
                for (int r = 0; r < 16; ++r) oa[ct][r] *= f;
        }
        const float negmS = -m * SCL;

        // P = exp2(fma(s, SCL, -m*SCL)); 4-way sum accumulators
        float s0 = 0.f, s1 = 0.f, s2 = 0.f, s3 = 0.f;
        #pragma unroll
        for (int ks = 0; ks < 2; ++ks)
            #pragma unroll
            for (int r = 0; r < 16; r += 4) {
                float p0 = __builtin_amdgcn_exp2f(__builtin_fmaf(sa[ks][r+0], SCL, negmS));
                float p1 = __builtin_amdgcn_exp2f(__builtin_fmaf(sa[ks][r+1], SCL, negmS));
                float p2 = __builtin_amdgcn_exp2f(__builtin_fmaf(sa[ks][r+2], SCL, negmS));
                float p3 = __builtin_amdgcn_exp2f(__builtin_fmaf(sa[ks][r+3], SCL, negmS));
                sa[ks][r+0] = p0; sa[ks][r+1] = p1; sa[ks][r+2] = p2; sa[ks][r+3] = p3;
                s0 += p0; s1 += p1; s2 += p2; s3 += p3;
            }
        float ts = (s0 + s1) + (s2 + s3);
        ts += __shfl_xor(ts, 32);
        li += ts;

        // P -> MFMA-A fragments: cvt_pk pairs + shfl_xor(32) half-swap (proven)
        bf16x8 pa[4];
        #pragma unroll
        for (int ks = 0; ks < 2; ++ks)
            #pragma unroll
            for (int kd = 0; kd < 2; ++kd) {
                unsigned c01 = cvtpk(sa[ks][8*kd+0], sa[ks][8*kd+1]);
                unsigned c23 = cvtpk(sa[ks][8*kd+2], sa[ks][8*kd+3]);
                unsigned c45 = cvtpk(sa[ks][8*kd+4], sa[ks][8*kd+5]);
                unsigned c67 = cvtpk(sa[ks][8*kd+6], sa[ks][8*kd+7]);
                unsigned x01 = (unsigned)__shfl_xor((int)c01, 32);
                unsigned x23 = (unsigned)__shfl_xor((int)c23, 32);
                unsigned x45 = (unsigned)__shfl_xor((int)c45, 32);
                unsigned x67 = (unsigned)__shfl_xor((int)c67, 32);
                u32x4 wv;
                wv.x = hi ? x45 : c01;
                wv.y = hi ? x67 : c23;
                wv.z = hi ? c45 : x01;
                wv.w = hi ? c67 : x23;
                pa[ks*2 + kd] = __builtin_bit_cast(bf16x8, wv);
            }

        // prefetch next V tile (in flight under PV + next QK^T + softmax)
        bf16x8 vn[4][2];
        LOADV(vn, ktn);

        // O^T += V^T P^T
        __builtin_amdgcn_s_setprio(1);
        #pragma unroll
        for (int j = 0; j < 4; ++j)
            #pragma unroll
            for (int ct = 0; ct < 2; ++ct)
                oa[ct] = __builtin_amdgcn_mfma_f32_32x32x16_bf16(vc[j][ct], pa[j], oa[ct], 0, 0, 0);
        __builtin_amdgcn_s_setprio(0);

        // rotate pipeline registers
        #pragma unroll
        for (int ks = 0; ks < 2; ++ks)
            #pragma unroll
            for (int cs = 0; cs < 4; ++cs) kc[ks][cs] = kn[ks][cs];
        #pragma unroll
        for (int j = 0; j < 4; ++j)
            #pragma unroll
            for (int ct = 0; ct < 2; ++ct) vc[j][ct] = vn[j][ct];
    }
#undef LOADK
#undef LOADV

    // epilogue: out = x + emb + O/l   (channel = ct*32 + g*8 + hi*4 + 0..3)
    const float inv = 1.0f / li;
    const size_t rowb = (size_t)(b * NT + qrow) * ND + h * NC;
    #pragma unroll
    for (int ct = 0; ct < 2; ++ct)
        #pragma unroll
        for (int g = 0; g < 4; ++g) {
            int ch = ct * 32 + g * 8 + hi * 4;
            float4 xv = *(const float4*)(x + rowb + ch);
            float4 ev = *(const float4*)(emb + (size_t)b * ND + h * NC + ch);
            float4 r;
            r.x = xv.x + ev.x + oa[ct][4*g+0] * inv;
            r.y = xv.y + ev.y + oa[ct][4*g+1] * inv;
            r.z = xv.z + ev.z + oa[ct][4*g+2] * inv;
            r.w = xv.w + ev.w + oa[ct][4*g+3] * inv;
            *(float4*)(out + rowb + ch) = r;
        }
}

// ---------------------------------------------------------------------------
extern "C" void kernel_launch(void* const* d_in, const int* in_sizes, int n_in,
                              void* d_out, int out_size, void* d_ws, size_t ws_size,
                              hipStream_t stream) {
    const float* x     = (const float*)d_in[0];
    const float* emb   = (const float*)d_in[1];
    const float* Wq    = (const float*)d_in[2];
    const float* Wk    = (const float*)d_in[3];
    const float* Wv    = (const float*)d_in[4];
    const float* gamma = (const float*)d_in[5];
    const float* beta  = (const float*)d_in[6];
    float* out = (float*)d_out;

    unsigned short* qbb = (unsigned short*)d_ws;
    unsigned short* kbb = qbb + (size_t)NM * ND;
    unsigned short* vtb = kbb + (size_t)NM * ND;
    unsigned short* xbb = vtb + (size_t)NM * ND;
    unsigned short* wb  = xbb + (size_t)NM * ND;

    ln_kernel<<<NM, 256, 0, stream>>>(x, gamma, beta, xbb);
    wconv_kernel<<<768, 256, 0, stream>>>(Wq, Wk, Wv, wb);
    qkv_gemm<<<dim3(4, 64, 3), 256, 0, stream>>>(xbb, wb, qbb, kbb, vtb);
    attn_kernel<<<dim3(16, NH, NB), 256, 0, stream>>>(qbb, kbb, vtb, x, emb, out);
}

// Round 10
// 119.937 us; speedup vs baseline: 1.3887x; 1.3887x over previous
//
#include <hip/hip_runtime.h>
#include <math.h>

#define NB 4
#define NT 2048
#define ND 512
#define NH 8
#define NC 64
#define NM (NB*NT)
#define LN_EPS 1e-5f
#define SCL 0.18033688f   // (1/sqrt(64)) * log2(e)

typedef __attribute__((ext_vector_type(8))) short bf16x8;
typedef __attribute__((ext_vector_type(4))) float f32x4;
typedef __attribute__((ext_vector_type(16))) float f32x16;
typedef __attribute__((ext_vector_type(4))) unsigned int u32x4;

__device__ inline unsigned short f2b(float f) {
    unsigned int u = __builtin_bit_cast(unsigned int, f);
    u += 0x7FFFu + ((u >> 16) & 1u);
    return (unsigned short)(u >> 16);
}
__device__ inline float b2f(unsigned short u) {
    return __builtin_bit_cast(float, (unsigned int)u << 16);
}
__device__ inline unsigned cvtpk(float lo, float hi) {
    unsigned r;
    asm("v_cvt_pk_bf16_f32 %0, %1, %2" : "=v"(r) : "v"(lo), "v"(hi));
    return r;
}
__device__ inline void gload_lds16(const void* g, void* l) {
    __builtin_amdgcn_global_load_lds(
        (__attribute__((address_space(1))) void*)g,
        (__attribute__((address_space(3))) void*)l, 16, 0, 0);
}

// ---------------------------------------------------------------------------
// LayerNorm -> bf16 xn.
// ---------------------------------------------------------------------------
__global__ __launch_bounds__(256) void ln_kernel(const float* __restrict__ x,
        const float* __restrict__ gamma, const float* __restrict__ beta,
        unsigned short* __restrict__ xb) {
    const int row = blockIdx.x;
    const float* xr = x + (size_t)row * ND;
    const int t = threadIdx.x;

    float2 v = *(const float2*)(xr + 2*t);
    float s  = v.x + v.y;
    float ss = v.x*v.x + v.y*v.y;
    #pragma unroll
    for (int off = 1; off < 64; off <<= 1) {
        s  += __shfl_xor(s, off);
        ss += __shfl_xor(ss, off);
    }
    __shared__ float sb[4], ssb[4];
    if ((t & 63) == 0) { sb[t >> 6] = s; ssb[t >> 6] = ss; }
    __syncthreads();
    s  = sb[0] + sb[1] + sb[2] + sb[3];
    ss = ssb[0] + ssb[1] + ssb[2] + ssb[3];

    const float mu   = s * (1.0f / ND);
    const float var  = ss * (1.0f / ND) - mu * mu;
    const float rstd = rsqrtf(var + LN_EPS);

    float2 g  = *(const float2*)(gamma + 2*t);
    float2 be = *(const float2*)(beta + 2*t);
    ushort2 o;
    o.x = f2b((v.x - mu) * rstd * g.x + be.x);
    o.y = f2b((v.y - mu) * rstd * g.y + be.y);
    *(ushort2*)(xb + (size_t)row * ND + 2*t) = o;
}

// ---------------------------------------------------------------------------
// W fp32 -> bf16
// ---------------------------------------------------------------------------
__global__ __launch_bounds__(256) void wconv_kernel(const float* __restrict__ Wq,
        const float* __restrict__ Wk, const float* __restrict__ Wv,
        unsigned short* __restrict__ wb) {
    int idx = blockIdx.x * 256 + threadIdx.x;
    const float* src = (idx < 65536) ? Wq : (idx < 131072) ? Wk : Wv;
    int loc = idx & 65535;
    float4 f = *(const float4*)(src + (size_t)loc * 4);
    ushort4 o;
    o.x = f2b(f.x); o.y = f2b(f.y); o.z = f2b(f.z); o.w = f2b(f.w);
    *(ushort4*)(wb + (size_t)idx * 4) = o;
}

// ---------------------------------------------------------------------------
// QKV projection: 128x128 tile, BK=64, bf16 MFMA.
// z==2 (V) writes transposed vt[b][h][c][t].
// ---------------------------------------------------------------------------
__global__ __launch_bounds__(256) void qkv_gemm(const unsigned short* __restrict__ xb,
        const unsigned short* __restrict__ wb,
        unsigned short* __restrict__ qb, unsigned short* __restrict__ kb,
        unsigned short* __restrict__ vtb) {
    const int z  = blockIdx.z;
    const int bm = blockIdx.y * 128;
    const int bn = blockIdx.x * 128;
    const int t  = threadIdx.x;
    const int w = t >> 6, l = t & 63, lr = l & 15, lg = l >> 4;
    const int wm = w >> 1, wn = w & 1;

    __shared__ __attribute__((aligned(16))) unsigned short As[128 * 64];
    __shared__ __attribute__((aligned(16))) unsigned short Bs[128 * 64];
    const unsigned short* Wp = wb + (size_t)z * ND * ND;

    f32x4 acc[4][4];
    #pragma unroll
    for (int i = 0; i < 4; ++i)
        #pragma unroll
        for (int j = 0; j < 4; ++j) acc[i][j] = (f32x4){0.f, 0.f, 0.f, 0.f};

    for (int k0 = 0; k0 < ND; k0 += 64) {
        __syncthreads();
        #pragma unroll
        for (int i = 0; i < 4; ++i) {
            int ch = i * 256 + t;
            int r = ch >> 3, c16 = ch & 7;
            gload_lds16(xb + (size_t)(bm + r) * ND + k0 + c16 * 8, (char*)As + ch * 16);
            gload_lds16(Wp + (size_t)(bn + r) * ND + k0 + c16 * 8, (char*)Bs + ch * 16);
        }
        __syncthreads();
        #pragma unroll
        for (int ks = 0; ks < 2; ++ks) {
            bf16x8 af[4], bfr[4];
            #pragma unroll
            for (int mf = 0; mf < 4; ++mf)
                af[mf] = *(const bf16x8*)((const char*)As + (wm*64 + mf*16 + lr)*128 + ks*64 + lg*16);
            #pragma unroll
            for (int nf = 0; nf < 4; ++nf)
                bfr[nf] = *(const bf16x8*)((const char*)Bs + (wn*64 + nf*16 + lr)*128 + ks*64 + lg*16);
            #pragma unroll
            for (int mf = 0; mf < 4; ++mf)
                #pragma unroll
                for (int nf = 0; nf < 4; ++nf)
                    acc[mf][nf] = __builtin_amdgcn_mfma_f32_16x16x32_bf16(
                        af[mf], bfr[nf], acc[mf][nf], 0, 0, 0);
        }
    }

    if (z < 2) {
        unsigned short* outp = (z == 0) ? qb : kb;
        #pragma unroll
        for (int mf = 0; mf < 4; ++mf)
            #pragma unroll
            for (int r = 0; r < 4; ++r) {
                int grow = bm + wm*64 + mf*16 + lg*4 + r;
                #pragma unroll
                for (int nf = 0; nf < 4; ++nf) {
                    int gcol = bn + wn*64 + nf*16 + lr;
                    outp[(size_t)grow * ND + gcol] = f2b(acc[mf][nf][r]);
                }
            }
    } else {
        #pragma unroll
        for (int mf = 0; mf < 4; ++mf)
            #pragma unroll
            for (int r = 0; r < 4; ++r) {
                int grow = bm + wm*64 + mf*16 + lg*4 + r;
                int bb = grow >> 11, tt = grow & 2047;
                #pragma unroll
                for (int nf = 0; nf < 4; ++nf) {
                    int gcol = bn + wn*64 + nf*16 + lr;
                    int h = gcol >> 6, c = gcol & 63;
                    vtb[((size_t)(bb * NH + h) * NC + c) * NT + tt] = f2b(acc[mf][nf][r]);
                }
            }
    }
}

// ---------------------------------------------------------------------------
// Flash attention: swapped 32x32x16, KV-split by 2, region pipeline (att[2]):
// region r = { barrier; STAGE(r+1); QK(r) || SM(r-1); PV(r-1) }.
// K double-buffered, V triple-buffered, saA/saB parity (static indexing).
// Numerics verbatim from passing round 6.
// ---------------------------------------------------------------------------
__device__ __forceinline__ void qk_tile(const char* __restrict__ Kc,
        const bf16x8* aq, f32x16* sa, const int q32, const int hi) {
    #pragma unroll
    for (int ks = 0; ks < 2; ++ks) {
        #pragma unroll
        for (int r = 0; r < 16; ++r) sa[ks][r] = 0.f;
        const int kr = ks * 32 + q32;
        #pragma unroll
        for (int cs = 0; cs < 4; ++cs) {
            int chunk = (cs*2 + hi) ^ (kr & 7);
            bf16x8 kf = *(const bf16x8*)(Kc + kr*128 + chunk*16);
            sa[ks] = __builtin_amdgcn_mfma_f32_32x32x16_bf16(kf, aq[cs], sa[ks], 0, 0, 0);
        }
    }
}

__device__ __forceinline__ void sm_tile(f32x16* sa, bf16x8* pa, f32x16* oa,
        float& m, float& li, const int hi) {
    // tile max: 3-input groups, cross-half via shfl_xor (proven)
    float a0 = fmaxf(fmaxf(sa[0][0],  sa[0][1]),  sa[0][2]);
    float a1 = fmaxf(fmaxf(sa[0][3],  sa[0][4]),  sa[0][5]);
    float a2 = fmaxf(fmaxf(sa[0][6],  sa[0][7]),  sa[0][8]);
    float a3 = fmaxf(fmaxf(sa[0][9],  sa[0][10]), sa[0][11]);
    float a4 = fmaxf(fmaxf(sa[0][12], sa[0][13]), sa[0][14]);
    float a5 = fmaxf(fmaxf(sa[0][15], sa[1][0]),  sa[1][1]);
    float a6 = fmaxf(fmaxf(sa[1][2],  sa[1][3]),  sa[1][4]);
    float a7 = fmaxf(fmaxf(sa[1][5],  sa[1][6]),  sa[1][7]);
    float a8 = fmaxf(fmaxf(sa[1][8],  sa[1][9]),  sa[1][10]);
    float a9 = fmaxf(fmaxf(sa[1][11], sa[1][12]), sa[1][13]);
    float b0 = fmaxf(fmaxf(a0, a1), a2);
    float b1 = fmaxf(fmaxf(a3, a4), a5);
    float b2 = fmaxf(fmaxf(a6, a7), a8);
    float b3 = fmaxf(fmaxf(a9, sa[1][14]), sa[1][15]);
    float tm = fmaxf(fmaxf(b0, b1), fmaxf(b2, b3));
    tm = fmaxf(tm, __shfl_xor(tm, 32));

    // defer-max (THR=8 in exp2 domain)
    if (__any((tm - m) * SCL > 8.0f)) {
        float nm = fmaxf(m, tm);
        float f = __builtin_amdgcn_exp2f((m - nm) * SCL);
        m = nm; li *= f;
        #pragma unroll
        for (int ct = 0; ct < 2; ++ct)
            #pragma unroll
            for (int r = 0; r < 16; ++r) oa[ct][r] *= f;
    }
    const float negmS = -m * SCL;

    // P = exp2(fma(s, SCL, -m*SCL)); 4-way sum accumulators
    float s0 = 0.f, s1 = 0.f, s2 = 0.f, s3 = 0.f;
    #pragma unroll
    for (int ks = 0; ks < 2; ++ks)
        #pragma unroll
        for (int r = 0; r < 16; r += 4) {
            float p0 = __builtin_amdgcn_exp2f(__builtin_fmaf(sa[ks][r+0], SCL, negmS));
            float p1 = __builtin_amdgcn_exp2f(__builtin_fmaf(sa[ks][r+1], SCL, negmS));
            float p2 = __builtin_amdgcn_exp2f(__builtin_fmaf(sa[ks][r+2], SCL, negmS));
            float p3 = __builtin_amdgcn_exp2f(__builtin_fmaf(sa[ks][r+3], SCL, negmS));
            sa[ks][r+0] = p0; sa[ks][r+1] = p1; sa[ks][r+2] = p2; sa[ks][r+3] = p3;
            s0 += p0; s1 += p1; s2 += p2; s3 += p3;
        }
    float ts = (s0 + s1) + (s2 + s3);
    ts += __shfl_xor(ts, 32);
    li += ts;

    // P -> MFMA-A fragments: cvt_pk pairs + shfl_xor(32) half-swap (proven)
    #pragma unroll
    for (int ks = 0; ks < 2; ++ks)
        #pragma unroll
        for (int kd = 0; kd < 2; ++kd) {
            unsigned c01 = cvtpk(sa[ks][8*kd+0], sa[ks][8*kd+1]);
            unsigned c23 = cvtpk(sa[ks][8*kd+2], sa[ks][8*kd+3]);
            unsigned c45 = cvtpk(sa[ks][8*kd+4], sa[ks][8*kd+5]);
            unsigned c67 = cvtpk(sa[ks][8*kd+6], sa[ks][8*kd+7]);
            unsigned x01 = (unsigned)__shfl_xor((int)c01, 32);
            unsigned x23 = (unsigned)__shfl_xor((int)c23, 32);
            unsigned x45 = (unsigned)__shfl_xor((int)c45, 32);
            unsigned x67 = (unsigned)__shfl_xor((int)c67, 32);
            u32x4 wv;
            wv.x = hi ? x45 : c01;
            wv.y = hi ? x67 : c23;
            wv.z = hi ? c45 : x01;
            wv.w = hi ? c67 : x23;
            pa[ks*2 + kd] = __builtin_bit_cast(bf16x8, wv);
        }
}

__device__ __forceinline__ void pv_tile(const char* __restrict__ Vc,
        const bf16x8* pa, f32x16* oa, const int q32, const int hi) {
    __builtin_amdgcn_s_setprio(1);
    #pragma unroll
    for (int j = 0; j < 4; ++j)
        #pragma unroll
        for (int ct = 0; ct < 2; ++ct) {
            int vr = ct * 32 + q32;
            int chunk = (j*2 + hi) ^ (vr & 7);
            bf16x8 vf = *(const bf16x8*)(Vc + vr*128 + chunk*16);
            oa[ct] = __builtin_amdgcn_mfma_f32_32x32x16_bf16(vf, pa[j], oa[ct], 0, 0, 0);
        }
    __builtin_amdgcn_s_setprio(0);
}

__global__ __launch_bounds__(256) void attn_kernel(
        const unsigned short* __restrict__ qb, const unsigned short* __restrict__ kb,
        const unsigned short* __restrict__ vtb,
        unsigned short* __restrict__ Opart, float* __restrict__ mlb) {
    const int b = blockIdx.z, h = blockIdx.y;
    const int qt = blockIdx.x & 15, half = blockIdx.x >> 4;
    const int koff = half * (NT / 2);
    const int t = threadIdx.x;
    const int w = t >> 6, l = t & 63;
    const int q32 = l & 31, hi = l >> 5;
    const int bh = b * NH + h;

    __shared__ __attribute__((aligned(16))) unsigned short Ks[2 * 64 * 64];  // 16 KB
    __shared__ __attribute__((aligned(16))) unsigned short Vs[3 * 64 * 64];  // 24 KB

    const size_t kbase = (size_t)(b * NT) * ND + h * NC;
    const size_t vbase = (size_t)bh * NC * NT;

#define STAGE(tile, kbi, vbi) do {                                              \
        _Pragma("unroll")                                                       \
        for (int i_ = 0; i_ < 2; ++i_) {                                        \
            int ch_ = i_ * 256 + t;                                             \
            int r_ = ch_ >> 3, c16_ = ch_ & 7;                                  \
            int c16s_ = c16_ ^ (r_ & 7);                                        \
            gload_lds16(kb + kbase + (size_t)(koff + (tile)*64 + r_) * ND + c16s_ * 8, \
                        (char*)Ks + (kbi) * 8192 + ch_ * 16);                   \
            gload_lds16(vtb + vbase + (size_t)r_ * NT + koff + (tile)*64 + c16s_ * 8,  \
                        (char*)Vs + (vbi) * 8192 + ch_ * 16);                   \
        }                                                                       \
    } while (0)

    const int qrow = qt * 128 + w * 32 + q32;
    bf16x8 aq[4];
    #pragma unroll
    for (int cs = 0; cs < 4; ++cs)
        aq[cs] = *(const bf16x8*)(qb + (size_t)(b*NT + qrow) * ND + h*NC + cs*16 + hi*8);

    f32x16 oa[2];
    #pragma unroll
    for (int ct = 0; ct < 2; ++ct)
        #pragma unroll
        for (int r = 0; r < 16; ++r) oa[ct][r] = 0.f;
    float m = -1e30f, li = 0.f;

    f32x16 saA[2], saB[2];
    bf16x8 pa[4];

    // region 0: stage(0) -> barrier -> stage(1), QK(0)
    STAGE(0, 0, 0);
    __syncthreads();
    STAGE(1, 1, 1);
    qk_tile((const char*)Ks, aq, saA, q32, hi);

    // regions 1..14, unrolled by 2 (parity: odd r -> saB, even r -> saA)
    for (int rr = 1; rr <= 13; rr += 2) {
        // region rr (odd): QK(rr)->saB; SM/PV(rr-1) from saA
        __syncthreads();
        STAGE(rr + 1, (rr + 1) & 1, (rr + 1) % 3);
        qk_tile((const char*)Ks + (rr & 1) * 8192, aq, saB, q32, hi);
        sm_tile(saA, pa, oa, m, li, hi);
        pv_tile((const char*)Vs + ((rr - 1) % 3) * 8192, pa, oa, q32, hi);
        // region rr+1 (even): QK(rr+1)->saA; SM/PV(rr) from saB
        __syncthreads();
        STAGE(rr + 2, (rr + 2) & 1, (rr + 2) % 3);
        qk_tile((const char*)Ks + ((rr + 1) & 1) * 8192, aq, saA, q32, hi);
        sm_tile(saB, pa, oa, m, li, hi);
        pv_tile((const char*)Vs + (rr % 3) * 8192, pa, oa, q32, hi);
    }

    // region 15: QK(15)->saB; SM/PV(14) from saA; then drain SM/PV(15)
    __syncthreads();
    qk_tile((const char*)Ks + 8192, aq, saB, q32, hi);
    sm_tile(saA, pa, oa, m, li, hi);
    pv_tile((const char*)Vs + (14 % 3) * 8192, pa, oa, q32, hi);
    sm_tile(saB, pa, oa, m, li, hi);
    pv_tile((const char*)Vs + (15 % 3) * 8192, pa, oa, q32, hi);
#undef STAGE

    // write bf16 partial O (layout [half][bh][q][c]) and (m, l)
    const int qq = qt * 128 + w * 32 + q32;
    size_t obase = ((size_t)(half * 32 + bh) * 2048 + qq) * 64;
    #pragma unroll
    for (int ct = 0; ct < 2; ++ct)
        #pragma unroll
        for (int g = 0; g < 4; ++g) {
            ushort4 ov;
            ov.x = f2b(oa[ct][4*g+0]); ov.y = f2b(oa[ct][4*g+1]);
            ov.z = f2b(oa[ct][4*g+2]); ov.w = f2b(oa[ct][4*g+3]);
            *(ushort4*)(Opart + obase + 32*ct + 8*g + 4*hi) = ov;
        }
    if (hi == 0)
        *(float2*)(mlb + ((size_t)(half * 32 + bh) * 2048 + qq) * 2) = make_float2(m, li);
}

// ---------------------------------------------------------------------------
// Combine the two KV-halves + fused residual epilogue.
// ---------------------------------------------------------------------------
__global__ __launch_bounds__(256) void combine_kernel(
        const unsigned short* __restrict__ Opart, const float* __restrict__ mlb,
        const float* __restrict__ x, const float* __restrict__ emb,
        float* __restrict__ out) {
    int tid = blockIdx.x * 256 + threadIdx.x;
    int qi = tid >> 4;
    int c4 = (tid & 15) * 4;
    int bh = qi >> 11, qq = qi & 2047;
    int b = bh >> 3, h = bh & 7;

    float2 ml0 = *(const float2*)(mlb + (size_t)qi * 2);
    float2 ml1 = *(const float2*)(mlb + ((size_t)65536 + qi) * 2);
    float M = fmaxf(ml0.x, ml1.x);
    float f0 = __builtin_amdgcn_exp2f((ml0.x - M) * SCL);
    float f1 = __builtin_amdgcn_exp2f((ml1.x - M) * SCL);
    float inv = 1.0f / (ml0.y * f0 + ml1.y * f1);

    ushort4 u0 = *(const ushort4*)(Opart + (size_t)qi * 64 + c4);
    ushort4 u1 = *(const ushort4*)(Opart + ((size_t)65536 + qi) * 64 + c4);

    size_t oidx = ((size_t)(b * NT) + qq) * ND + h * NC + c4;
    float4 xv = *(const float4*)(x + oidx);
    float4 ev = *(const float4*)(emb + (size_t)b * ND + h * NC + c4);
    float4 r;
    r.x = xv.x + ev.x + (b2f(u0.x) * f0 + b2f(u1.x) * f1) * inv;
    r.y = xv.y + ev.y + (b2f(u0.y) * f0 + b2f(u1.y) * f1) * inv;
    r.z = xv.z + ev.z + (b2f(u0.z) * f0 + b2f(u1.z) * f1) * inv;
    r.w = xv.w + ev.w + (b2f(u0.w) * f0 + b2f(u1.w) * f1) * inv;
    *(float4*)(out + oidx) = r;
}

// ---------------------------------------------------------------------------
extern "C" void kernel_launch(void* const* d_in, const int* in_sizes, int n_in,
                              void* d_out, int out_size, void* d_ws, size_t ws_size,
                              hipStream_t stream) {
    const float* x     = (const float*)d_in[0];
    const float* emb   = (const float*)d_in[1];
    const float* Wq    = (const float*)d_in[2];
    const float* Wk    = (const float*)d_in[3];
    const float* Wv    = (const float*)d_in[4];
    const float* gamma = (const float*)d_in[5];
    const float* beta  = (const float*)d_in[6];
    float* out = (float*)d_out;

    unsigned short* qbb = (unsigned short*)d_ws;
    unsigned short* kbb = qbb + (size_t)NM * ND;
    unsigned short* vtb = kbb + (size_t)NM * ND;
    unsigned short* xbb = vtb + (size_t)NM * ND;
    unsigned short* wb  = xbb + (size_t)NM * ND;
    unsigned short* Opart = xbb;
    float* mlb = (float*)(xbb + (size_t)2 * 65536 * 64);

    ln_kernel<<<NM, 256, 0, stream>>>(x, gamma, beta, xbb);
    wconv_kernel<<<768, 256, 0, stream>>>(Wq, Wk, Wv, wb);
    qkv_gemm<<<dim3(4, 64, 3), 256, 0, stream>>>(xbb, wb, qbb, kbb, vtb);
    attn_kernel<<<dim3(32, NH, NB), 256, 0, stream>>>(qbb, kbb, vtb, Opart, mlb);
    combine_kernel<<<4096, 256, 0, stream>>>(Opart, mlb, x, emb, out);
}

// Round 11
// 106.134 us; speedup vs baseline: 1.5693x; 1.1301x over previous
//
#include <hip/hip_runtime.h>
#include <math.h>

#define NB 4
#define NT 2048
#define ND 512
#define NH 8
#define NC 64
#define NM (NB*NT)
#define LN_EPS 1e-5f
#define SCL 0.18033688f   // (1/sqrt(64)) * log2(e)

typedef __attribute__((ext_vector_type(8))) short bf16x8;
typedef __attribute__((ext_vector_type(4))) float f32x4;
typedef __attribute__((ext_vector_type(16))) float f32x16;
typedef __attribute__((ext_vector_type(4))) unsigned int u32x4;

__device__ inline unsigned short f2b(float f) {
    unsigned int u = __builtin_bit_cast(unsigned int, f);
    u += 0x7FFFu + ((u >> 16) & 1u);
    return (unsigned short)(u >> 16);
}
__device__ inline float b2f(unsigned short u) {
    return __builtin_bit_cast(float, (unsigned int)u << 16);
}
__device__ inline unsigned cvtpk(float lo, float hi) {
    unsigned r;
    asm("v_cvt_pk_bf16_f32 %0, %1, %2" : "=v"(r) : "v"(lo), "v"(hi));
    return r;
}
__device__ inline void gload_lds16(const void* g, void* l) {
    __builtin_amdgcn_global_load_lds(
        (__attribute__((address_space(1))) void*)g,
        (__attribute__((address_space(3))) void*)l, 16, 0, 0);
}

// ---------------------------------------------------------------------------
// LayerNorm -> bf16 xn.
// ---------------------------------------------------------------------------
__global__ __launch_bounds__(256) void ln_kernel(const float* __restrict__ x,
        const float* __restrict__ gamma, const float* __restrict__ beta,
        unsigned short* __restrict__ xb) {
    const int row = blockIdx.x;
    const float* xr = x + (size_t)row * ND;
    const int t = threadIdx.x;

    float2 v = *(const float2*)(xr + 2*t);
    float s  = v.x + v.y;
    float ss = v.x*v.x + v.y*v.y;
    #pragma unroll
    for (int off = 1; off < 64; off <<= 1) {
        s  += __shfl_xor(s, off);
        ss += __shfl_xor(ss, off);
    }
    __shared__ float sb[4], ssb[4];
    if ((t & 63) == 0) { sb[t >> 6] = s; ssb[t >> 6] = ss; }
    __syncthreads();
    s  = sb[0] + sb[1] + sb[2] + sb[3];
    ss = ssb[0] + ssb[1] + ssb[2] + ssb[3];

    const float mu   = s * (1.0f / ND);
    const float var  = ss * (1.0f / ND) - mu * mu;
    const float rstd = rsqrtf(var + LN_EPS);

    float2 g  = *(const float2*)(gamma + 2*t);
    float2 be = *(const float2*)(beta + 2*t);
    ushort2 o;
    o.x = f2b((v.x - mu) * rstd * g.x + be.x);
    o.y = f2b((v.y - mu) * rstd * g.y + be.y);
    *(ushort2*)(xb + (size_t)row * ND + 2*t) = o;
}

// ---------------------------------------------------------------------------
// W fp32 -> bf16
// ---------------------------------------------------------------------------
__global__ __launch_bounds__(256) void wconv_kernel(const float* __restrict__ Wq,
        const float* __restrict__ Wk, const float* __restrict__ Wv,
        unsigned short* __restrict__ wb) {
    int idx = blockIdx.x * 256 + threadIdx.x;
    const float* src = (idx < 65536) ? Wq : (idx < 131072) ? Wk : Wv;
    int loc = idx & 65535;
    float4 f = *(const float4*)(src + (size_t)loc * 4);
    ushort4 o;
    o.x = f2b(f.x); o.y = f2b(f.y); o.z = f2b(f.z); o.w = f2b(f.w);
    *(ushort4*)(wb + (size_t)idx * 4) = o;
}

// ---------------------------------------------------------------------------
// QKV projection: 128x128 tile, BK=64, bf16 MFMA.
// z==2 (V) writes transposed vt[b][h][c][t].
// ---------------------------------------------------------------------------
__global__ __launch_bounds__(256) void qkv_gemm(const unsigned short* __restrict__ xb,
        const unsigned short* __restrict__ wb,
        unsigned short* __restrict__ qb, unsigned short* __restrict__ kb,
        unsigned short* __restrict__ vtb) {
    const int z  = blockIdx.z;
    const int bm = blockIdx.y * 128;
    const int bn = blockIdx.x * 128;
    const int t  = threadIdx.x;
    const int w = t >> 6, l = t & 63, lr = l & 15, lg = l >> 4;
    const int wm = w >> 1, wn = w & 1;

    __shared__ __attribute__((aligned(16))) unsigned short As[128 * 64];
    __shared__ __attribute__((aligned(16))) unsigned short Bs[128 * 64];
    const unsigned short* Wp = wb + (size_t)z * ND * ND;

    f32x4 acc[4][4];
    #pragma unroll
    for (int i = 0; i < 4; ++i)
        #pragma unroll
        for (int j = 0; j < 4; ++j) acc[i][j] = (f32x4){0.f, 0.f, 0.f, 0.f};

    for (int k0 = 0; k0 < ND; k0 += 64) {
        __syncthreads();
        #pragma unroll
        for (int i = 0; i < 4; ++i) {
            int ch = i * 256 + t;
            int r = ch >> 3, c16 = ch & 7;
            gload_lds16(xb + (size_t)(bm + r) * ND + k0 + c16 * 8, (char*)As + ch * 16);
            gload_lds16(Wp + (size_t)(bn + r) * ND + k0 + c16 * 8, (char*)Bs + ch * 16);
        }
        __syncthreads();
        #pragma unroll
        for (int ks = 0; ks < 2; ++ks) {
            bf16x8 af[4], bfr[4];
            #pragma unroll
            for (int mf = 0; mf < 4; ++mf)
                af[mf] = *(const bf16x8*)((const char*)As + (wm*64 + mf*16 + lr)*128 + ks*64 + lg*16);
            #pragma unroll
            for (int nf = 0; nf < 4; ++nf)
                bfr[nf] = *(const bf16x8*)((const char*)Bs + (wn*64 + nf*16 + lr)*128 + ks*64 + lg*16);
            #pragma unroll
            for (int mf = 0; mf < 4; ++mf)
                #pragma unroll
                for (int nf = 0; nf < 4; ++nf)
                    acc[mf][nf] = __builtin_amdgcn_mfma_f32_16x16x32_bf16(
                        af[mf], bfr[nf], acc[mf][nf], 0, 0, 0);
        }
    }

    if (z < 2) {
        unsigned short* outp = (z == 0) ? qb : kb;
        #pragma unroll
        for (int mf = 0; mf < 4; ++mf)
            #pragma unroll
            for (int r = 0; r < 4; ++r) {
                int grow = bm + wm*64 + mf*16 + lg*4 + r;
                #pragma unroll
                for (int nf = 0; nf < 4; ++nf) {
                    int gcol = bn + wn*64 + nf*16 + lr;
                    outp[(size_t)grow * ND + gcol] = f2b(acc[mf][nf][r]);
                }
            }
    } else {
        #pragma unroll
        for (int mf = 0; mf < 4; ++mf)
            #pragma unroll
            for (int r = 0; r < 4; ++r) {
                int grow = bm + wm*64 + mf*16 + lg*4 + r;
                int bb = grow >> 11, tt = grow & 2047;
                #pragma unroll
                for (int nf = 0; nf < 4; ++nf) {
                    int gcol = bn + wn*64 + nf*16 + lr;
                    int h = gcol >> 6, c = gcol & 63;
                    vtb[((size_t)(bb * NH + h) * NC + c) * NT + tt] = f2b(acc[mf][nf][r]);
                }
            }
    }
}

// ---------------------------------------------------------------------------
// Flash attention, swapped 32x32x16, KV-split by 2.
// THIS ROUND: 8-wave blocks (256 q-rows) -- staging amortized over 2x MFMAs,
// 16 waves/CU. Sync structure + numerics verbatim from passing round 6.
// ---------------------------------------------------------------------------
__device__ __forceinline__ void attn_tile(
        const char* __restrict__ Kc, const char* __restrict__ Vc,
        const bf16x8* aq, f32x16* oa, float& m, float& li,
        const int q32, const int hi) {
    // S^T = K Q^T : lane owns query q32(+hi partner), 32 keys in regs
    f32x16 sa[2];
    __builtin_amdgcn_s_setprio(1);
    #pragma unroll
    for (int ks = 0; ks < 2; ++ks) {
        #pragma unroll
        for (int r = 0; r < 16; ++r) sa[ks][r] = 0.f;
        const int kr = ks * 32 + q32;
        #pragma unroll
        for (int cs = 0; cs < 4; ++cs) {
            int chunk = (cs*2 + hi) ^ (kr & 7);
            bf16x8 kf = *(const bf16x8*)(Kc + kr*128 + chunk*16);
            sa[ks] = __builtin_amdgcn_mfma_f32_32x32x16_bf16(kf, aq[cs], sa[ks], 0, 0, 0);
        }
    }
    __builtin_amdgcn_s_setprio(0);

    // tile max: 3-input groups (v_max3 fusion), cross-half via shfl_xor
    float a0 = fmaxf(fmaxf(sa[0][0],  sa[0][1]),  sa[0][2]);
    float a1 = fmaxf(fmaxf(sa[0][3],  sa[0][4]),  sa[0][5]);
    float a2 = fmaxf(fmaxf(sa[0][6],  sa[0][7]),  sa[0][8]);
    float a3 = fmaxf(fmaxf(sa[0][9],  sa[0][10]), sa[0][11]);
    float a4 = fmaxf(fmaxf(sa[0][12], sa[0][13]), sa[0][14]);
    float a5 = fmaxf(fmaxf(sa[0][15], sa[1][0]),  sa[1][1]);
    float a6 = fmaxf(fmaxf(sa[1][2],  sa[1][3]),  sa[1][4]);
    float a7 = fmaxf(fmaxf(sa[1][5],  sa[1][6]),  sa[1][7]);
    float a8 = fmaxf(fmaxf(sa[1][8],  sa[1][9]),  sa[1][10]);
    float a9 = fmaxf(fmaxf(sa[1][11], sa[1][12]), sa[1][13]);
    float b0 = fmaxf(fmaxf(a0, a1), a2);
    float b1 = fmaxf(fmaxf(a3, a4), a5);
    float b2 = fmaxf(fmaxf(a6, a7), a8);
    float b3 = fmaxf(fmaxf(a9, sa[1][14]), sa[1][15]);
    float tm = fmaxf(fmaxf(b0, b1), fmaxf(b2, b3));
    tm = fmaxf(tm, __shfl_xor(tm, 32));

    // defer-max (THR=8 in exp2 domain)
    if (__any((tm - m) * SCL > 8.0f)) {
        float nm = fmaxf(m, tm);
        float f = __builtin_amdgcn_exp2f((m - nm) * SCL);
        m = nm; li *= f;
        #pragma unroll
        for (int ct = 0; ct < 2; ++ct)
            #pragma unroll
            for (int r = 0; r < 16; ++r) oa[ct][r] *= f;
    }
    const float negmS = -m * SCL;

    // P = exp2(fma(s, SCL, -m*SCL)); 4-way sum accumulators
    float s0 = 0.f, s1 = 0.f, s2 = 0.f, s3 = 0.f;
    #pragma unroll
    for (int ks = 0; ks < 2; ++ks)
        #pragma unroll
        for (int r = 0; r < 16; r += 4) {
            float p0 = __builtin_amdgcn_exp2f(__builtin_fmaf(sa[ks][r+0], SCL, negmS));
            float p1 = __builtin_amdgcn_exp2f(__builtin_fmaf(sa[ks][r+1], SCL, negmS));
            float p2 = __builtin_amdgcn_exp2f(__builtin_fmaf(sa[ks][r+2], SCL, negmS));
            float p3 = __builtin_amdgcn_exp2f(__builtin_fmaf(sa[ks][r+3], SCL, negmS));
            sa[ks][r+0] = p0; sa[ks][r+1] = p1; sa[ks][r+2] = p2; sa[ks][r+3] = p3;
            s0 += p0; s1 += p1; s2 += p2; s3 += p3;
        }
    float ts = (s0 + s1) + (s2 + s3);
    ts += __shfl_xor(ts, 32);
    li += ts;

    // P -> MFMA-A fragments: cvt_pk pairs + shfl_xor(32) half-swap (proven)
    bf16x8 pa[4];
    #pragma unroll
    for (int ks = 0; ks < 2; ++ks)
        #pragma unroll
        for (int kd = 0; kd < 2; ++kd) {
            unsigned c01 = cvtpk(sa[ks][8*kd+0], sa[ks][8*kd+1]);
            unsigned c23 = cvtpk(sa[ks][8*kd+2], sa[ks][8*kd+3]);
            unsigned c45 = cvtpk(sa[ks][8*kd+4], sa[ks][8*kd+5]);
            unsigned c67 = cvtpk(sa[ks][8*kd+6], sa[ks][8*kd+7]);
            unsigned x01 = (unsigned)__shfl_xor((int)c01, 32);
            unsigned x23 = (unsigned)__shfl_xor((int)c23, 32);
            unsigned x45 = (unsigned)__shfl_xor((int)c45, 32);
            unsigned x67 = (unsigned)__shfl_xor((int)c67, 32);
            u32x4 wv;
            wv.x = hi ? x45 : c01;
            wv.y = hi ? x67 : c23;
            wv.z = hi ? c45 : x01;
            wv.w = hi ? c67 : x23;
            pa[ks*2 + kd] = __builtin_bit_cast(bf16x8, wv);
        }

    // O^T += V^T P^T
    __builtin_amdgcn_s_setprio(1);
    #pragma unroll
    for (int j = 0; j < 4; ++j)
        #pragma unroll
        for (int ct = 0; ct < 2; ++ct) {
            int vr = ct * 32 + q32;
            int chunk = (j*2 + hi) ^ (vr & 7);
            bf16x8 vf = *(const bf16x8*)(Vc + vr*128 + chunk*16);
            oa[ct] = __builtin_amdgcn_mfma_f32_32x32x16_bf16(vf, pa[j], oa[ct], 0, 0, 0);
        }
    __builtin_amdgcn_s_setprio(0);
}

__global__ __launch_bounds__(512) void attn_kernel(
        const unsigned short* __restrict__ qb, const unsigned short* __restrict__ kb,
        const unsigned short* __restrict__ vtb,
        unsigned short* __restrict__ Opart, float* __restrict__ mlb) {
    const int b = blockIdx.z, h = blockIdx.y;
    const int qt = blockIdx.x & 7, half = blockIdx.x >> 3;
    const int koff = half * (NT / 2);
    const int t = threadIdx.x;
    const int w = t >> 6, l = t & 63;
    const int q32 = l & 31, hi = l >> 5;
    const int bh = b * NH + h;

    __shared__ __attribute__((aligned(16))) unsigned short Ks[2 * 64 * 64];
    __shared__ __attribute__((aligned(16))) unsigned short Vs[2 * 64 * 64];

    const size_t kbase = (size_t)(b * NT) * ND + h * NC;
    const size_t vbase = (size_t)bh * NC * NT;

#define STAGE(bi, kt0) do {                                                     \
        int ch_ = t;                       /* 512 thr x 16B = 8KB per buffer */ \
        int r_ = ch_ >> 3, c16_ = ch_ & 7;                                      \
        int c16s_ = c16_ ^ (r_ & 7);                                            \
        gload_lds16(kb + kbase + (size_t)(koff + (kt0) + r_) * ND + c16s_ * 8,  \
                    (char*)Ks + (bi) * 8192 + ch_ * 16);                        \
        gload_lds16(vtb + vbase + (size_t)r_ * NT + koff + (kt0) + c16s_ * 8,   \
                    (char*)Vs + (bi) * 8192 + ch_ * 16);                        \
    } while (0)

    const int qrow = qt * 256 + w * 32 + q32;
    bf16x8 aq[4];
    #pragma unroll
    for (int cs = 0; cs < 4; ++cs)
        aq[cs] = *(const bf16x8*)(qb + (size_t)(b*NT + qrow) * ND + h*NC + cs*16 + hi*8);

    f32x16 oa[2];
    #pragma unroll
    for (int ct = 0; ct < 2; ++ct)
        #pragma unroll
        for (int r = 0; r < 16; ++r) oa[ct][r] = 0.f;
    float m = -1e30f, li = 0.f;

    STAGE(0, 0);
    __syncthreads();

    for (int kt = 0; kt < NT/2; kt += 128) {
        STAGE(1, kt + 64);
        attn_tile((const char*)Ks, (const char*)Vs, aq, oa, m, li, q32, hi);
        __syncthreads();
        if (kt + 128 < NT/2) STAGE(0, kt + 128);
        attn_tile((const char*)Ks + 8192, (const char*)Vs + 8192, aq, oa, m, li, q32, hi);
        __syncthreads();
    }
#undef STAGE

    // write bf16 partial O (layout [half][bh][q][c]) and (m, l)
    const int qq = qt * 256 + w * 32 + q32;
    size_t obase = ((size_t)(half * 32 + bh) * 2048 + qq) * 64;
    #pragma unroll
    for (int ct = 0; ct < 2; ++ct)
        #pragma unroll
        for (int g = 0; g < 4; ++g) {
            ushort4 ov;
            ov.x = f2b(oa[ct][4*g+0]); ov.y = f2b(oa[ct][4*g+1]);
            ov.z = f2b(oa[ct][4*g+2]); ov.w = f2b(oa[ct][4*g+3]);
            *(ushort4*)(Opart + obase + 32*ct + 8*g + 4*hi) = ov;
        }
    if (hi == 0)
        *(float2*)(mlb + ((size_t)(half * 32 + bh) * 2048 + qq) * 2) = make_float2(m, li);
}

// ---------------------------------------------------------------------------
// Combine the two KV-halves + fused residual epilogue.
// ---------------------------------------------------------------------------
__global__ __launch_bounds__(256) void combine_kernel(
        const unsigned short* __restrict__ Opart, const float* __restrict__ mlb,
        const float* __restrict__ x, const float* __restrict__ emb,
        float* __restrict__ out) {
    int tid = blockIdx.x * 256 + threadIdx.x;
    int qi = tid >> 4;
    int c4 = (tid & 15) * 4;
    int bh = qi >> 11, qq = qi & 2047;
    int b = bh >> 3, h = bh & 7;

    float2 ml0 = *(const float2*)(mlb + (size_t)qi * 2);
    float2 ml1 = *(const float2*)(mlb + ((size_t)65536 + qi) * 2);
    float M = fmaxf(ml0.x, ml1.x);
    float f0 = __builtin_amdgcn_exp2f((ml0.x - M) * SCL);
    float f1 = __builtin_amdgcn_exp2f((ml1.x - M) * SCL);
    float inv = 1.0f / (ml0.y * f0 + ml1.y * f1);

    ushort4 u0 = *(const ushort4*)(Opart + (size_t)qi * 64 + c4);
    ushort4 u1 = *(const ushort4*)(Opart + ((size_t)65536 + qi) * 64 + c4);

    size_t oidx = ((size_t)(b * NT) + qq) * ND + h * NC + c4;
    float4 xv = *(const float4*)(x + oidx);
    float4 ev = *(const float4*)(emb + (size_t)b * ND + h * NC + c4);
    float4 r;
    r.x = xv.x + ev.x + (b2f(u0.x) * f0 + b2f(u1.x) * f1) * inv;
    r.y = xv.y + ev.y + (b2f(u0.y) * f0 + b2f(u1.y) * f1) * inv;
    r.z = xv.z + ev.z + (b2f(u0.z) * f0 + b2f(u1.z) * f1) * inv;
    r.w = xv.w + ev.w + (b2f(u0.w) * f0 + b2f(u1.w) * f1) * inv;
    *(float4*)(out + oidx) = r;
}

// ---------------------------------------------------------------------------
extern "C" void kernel_launch(void* const* d_in, const int* in_sizes, int n_in,
                              void* d_out, int out_size, void* d_ws, size_t ws_size,
                              hipStream_t stream) {
    const float* x     = (const float*)d_in[0];
    const float* emb   = (const float*)d_in[1];
    const float* Wq    = (const float*)d_in[2];
    const float* Wk    = (const float*)d_in[3];
    const float* Wv    = (const float*)d_in[4];
    const float* gamma = (const float*)d_in[5];
    const float* beta  = (const float*)d_in[6];
    float* out = (float*)d_out;

    unsigned short* qbb = (unsigned short*)d_ws;
    unsigned short* kbb = qbb + (size_t)NM * ND;
    unsigned short* vtb = kbb + (size_t)NM * ND;
    unsigned short* xbb = vtb + (size_t)NM * ND;
    unsigned short* wb  = xbb + (size_t)NM * ND;
    unsigned short* Opart = xbb;
    float* mlb = (float*)(xbb + (size_t)2 * 65536 * 64);

    ln_kernel<<<NM, 256, 0, stream>>>(x, gamma, beta, xbb);
    wconv_kernel<<<768, 256, 0, stream>>>(Wq, Wk, Wv, wb);
    qkv_gemm<<<dim3(4, 64, 3), 256, 0, stream>>>(xbb, wb, qbb, kbb, vtb);
    attn_kernel<<<dim3(16, NH, NB), 512, 0, stream>>>(qbb, kbb, vtb, Opart, mlb);
    combine_kernel<<<4096, 256, 0, stream>>>(Opart, mlb, x, emb, out);
}